// Round 1
// baseline (1023.563 us; speedup 1.0000x reference)
//
#include <hip/hip_runtime.h>

// Segment-mean pooling: x is (BATCH*49, 512) fp32 with 49 contiguous rows
// per graph (batch = repeat(arange(BATCH), 49)); out is (BATCH, 512) fp32
// row-means. Memory-bound streaming kernel: one thread per float4 output
// column, coalesced reads, no reuse -> no LDS needed.

#define GRIDN 49          // nodes per graph (7x7)
#define FDIM  512         // feature dim
#define FVEC  (FDIM / 4)  // float4 columns per row = 128

__global__ __launch_bounds__(256) void graph_pool_mean_kernel(
    const float* __restrict__ x, float* __restrict__ out, int num_graphs) {
    int idx = blockIdx.x * blockDim.x + threadIdx.x;  // one float4 column
    int b = idx >> 7;          // graph index (FVEC == 128)
    int c = idx & (FVEC - 1);  // float4 column within the row
    if (b >= num_graphs) return;

    const float4* xp = (const float4*)x + (size_t)b * GRIDN * FVEC + c;
    float4 acc = make_float4(0.f, 0.f, 0.f, 0.f);
    // 49 = 7*7; unroll by 7 keeps ~7 float4 loads in flight per thread
    // without blowing the VGPR budget (full unroll would want ~196 VGPRs).
#pragma unroll 7
    for (int g = 0; g < GRIDN; ++g) {
        float4 v = xp[(size_t)g * FVEC];
        acc.x += v.x;
        acc.y += v.y;
        acc.z += v.z;
        acc.w += v.w;
    }
    const float s = 1.0f / (float)GRIDN;
    float4 r = make_float4(acc.x * s, acc.y * s, acc.z * s, acc.w * s);
    ((float4*)out)[(size_t)b * FVEC + c] = r;
}

extern "C" void kernel_launch(void* const* d_in, const int* in_sizes, int n_in,
                              void* d_out, int out_size, void* d_ws, size_t ws_size,
                              hipStream_t stream) {
    const float* x = (const float*)d_in[0];
    // d_in[1] = batch ids (contiguous, 49 per graph — layout is static),
    // d_in[2] = grid_size (7). Both implied by the fixed layout.
    float* out = (float*)d_out;

    int num_graphs = out_size / FDIM;  // 8192
    int total_threads = num_graphs * FVEC;
    int block = 256;
    int grid = (total_threads + block - 1) / block;
    graph_pool_mean_kernel<<<grid, block, 0, stream>>>(x, out, num_graphs);
}